// Round 14
// baseline (1506.077 us; speedup 1.0000x reference)
//
#include <hip/hip_runtime.h>
#include <math.h>

#define RTOT 19200          // rows per feature map (4*4800)
#define RALL 38400          // both feature maps batched
#define CDIM 256
#define SLEN 4800
#define NB 8                // total batches (0-3 = feat0, 4-7 = feat1)
#define NHEAD 8
#define SEG 25
#define SCHUNK 192          // SLEN/SEG

typedef __attribute__((ext_vector_type(8))) short short8v;
typedef __attribute__((ext_vector_type(4))) float f32x4;

__device__ __forceinline__ ushort f2b(float f) {           // fp32 -> bf16 RNE
    unsigned u = __float_as_uint(f);
    unsigned r = (u + 0x7FFFu + ((u >> 16) & 1u)) >> 16;
    return (ushort)r;
}
__device__ __forceinline__ float b2f(ushort u) {
    return __uint_as_float(((unsigned)u) << 16);
}

__device__ __forceinline__ float elu1(float v) { return v > 0.0f ? v + 1.0f : __expf(v); }

__device__ __forceinline__ void gload16(const void* g, void* l) {
    __builtin_amdgcn_global_load_lds((const __attribute__((address_space(1))) void*)g,
                                     (__attribute__((address_space(3))) void*)l, 16, 0, 0);
}

// Entry sync: counted vmcnt + barrier, fully fenced (no instr may cross).
#define WAIT_BAR(N) do { \
    __builtin_amdgcn_sched_barrier(0); \
    asm volatile("s_waitcnt vmcnt(" #N ")\n\ts_barrier" ::: "memory"); \
    __builtin_amdgcn_sched_barrier(0); \
} while (0)
// Exit sync: drain LDS reads into registers BEFORE the barrier (rule #18 —
// MFMAs may be scheduled after; their operands must already be in regs),
// so the buffer can be safely overwritten by other waves' next stage.
#define END_BAR() do { \
    __builtin_amdgcn_sched_barrier(0); \
    asm volatile("s_waitcnt lgkmcnt(0)\n\ts_barrier" ::: "memory"); \
    __builtin_amdgcn_sched_barrier(0); \
} while (0)

// ---------------- QKV GEMM: split(xb @ [Wq|Wk|Wv]), 3-deep counted-vmcnt pipeline ----------------
__global__ __launch_bounds__(256) void qkv_gemm(
    const ushort* __restrict__ A, const ushort* __restrict__ Bt,
    ushort* __restrict__ Oq, ushort* __restrict__ Ok, ushort* __restrict__ Ov)
{
    __shared__ __align__(16) ushort As[3][128 * 32];
    __shared__ __align__(16) ushort Bs[3][128 * 32];
    const int t = threadIdx.x;
    const int wave = t >> 6, lane = t & 63;
    const int bm = blockIdx.y * 128, bn = blockIdx.x * 128;
    const int wr = wave >> 1, wc = wave & 1;
    const int lr = lane & 15, lk = (lane >> 4) * 8;

    const int srow = t >> 2;
    const int sgrp = ((t & 3) * 8) ^ ((srow & 3) * 8);
    const ushort* bAr = A + (size_t)(bm + srow) * 256 + sgrp;
    const ushort* bBr = Bt + (size_t)(bn + srow) * 256 + sgrp;

    const f32x4 z4 = {0.f, 0.f, 0.f, 0.f};
    f32x4 acc[4][4];
    #pragma unroll
    for (int m = 0; m < 4; ++m)
        #pragma unroll
        for (int n = 0; n < 4; ++n) acc[m][n] = z4;

    auto stage = [&](int k0, int b) {           // 4 loads per wave
        char* la = (char*)As[b] + wave * 1024;
        char* lb = (char*)Bs[b] + wave * 1024;
        gload16(bAr + k0, la);
        gload16(bAr + k0 + 64 * 256, la + 4096);
        gload16(bBr + k0, lb);
        gload16(bBr + k0 + 64 * 256, lb + 4096);
    };

    stage(0, 0);
    stage(32, 1);
    int cur = 0;
    for (int ti = 0; ti < 8; ++ti) {
        if (ti < 6) {
            stage((ti + 2) * 32, (cur + 2) % 3);
            WAIT_BAR(8);          // 12 outstanding -> oldest 4 (buf[cur]) retired
        } else if (ti == 6) {
            WAIT_BAR(4);          // tail drain
        } else {
            WAIT_BAR(0);
        }
        short8v af[4], bfr[4];
        #pragma unroll
        for (int m = 0; m < 4; ++m) {
            const int r = wr * 64 + m * 16 + lr;
            af[m] = *(const short8v*)&As[cur][r * 32 + (lk ^ ((r & 3) * 8))];
        }
        #pragma unroll
        for (int n = 0; n < 4; ++n) {
            const int r = wc * 64 + n * 16 + lr;
            bfr[n] = *(const short8v*)&Bs[cur][r * 32 + (lk ^ ((r & 3) * 8))];
        }
        #pragma unroll
        for (int m = 0; m < 4; ++m)
            #pragma unroll
            for (int n = 0; n < 4; ++n)
                acc[m][n] = __builtin_amdgcn_mfma_f32_16x16x32_bf16(af[m], bfr[n], acc[m][n], 0, 0, 0);
        END_BAR();                // ds_reads drained -> buffer reusable
        cur = (cur + 1) % 3;
    }

    const int orow = bm + wr * 64 + (lane >> 4) * 4;
    const int ocol = bn + wc * 64 + lr;
    #pragma unroll
    for (int m = 0; m < 4; ++m)
        #pragma unroll
        for (int n = 0; n < 4; ++n)
            #pragma unroll
            for (int j = 0; j < 4; ++j) {
                const float v = acc[m][n][j];
                const size_t row = (size_t)(orow + m * 16 + j);
                const int col = ocol + n * 16;
                const int seg = col >> 8, c = col & 255;
                ushort* dst = seg == 0 ? Oq : (seg == 1 ? Ok : Ov);
                dst[row * 256 + c] = f2b(seg < 2 ? elu1(v) : v);
            }
}

// ---------------- W1 GEMM: h1 = relu(concat(xb, mln) @ W1), 128x128 tile, 3-deep pipeline ----------------
__global__ __launch_bounds__(256) void w1_gemm(
    const ushort* __restrict__ A, const ushort* __restrict__ A2,
    const ushort* __restrict__ Bt, ushort* __restrict__ O)
{
    __shared__ __align__(16) ushort As[3][128 * 32];
    __shared__ __align__(16) ushort Bs[3][128 * 32];
    const int t = threadIdx.x;
    const int wave = t >> 6, lane = t & 63;
    const int bm = blockIdx.y * 128, bn = blockIdx.x * 128;
    const int wr = wave >> 1, wc = wave & 1;
    const int lr = lane & 15, lk = (lane >> 4) * 8;

    const int srow = t >> 2;
    const int sgrp = ((t & 3) * 8) ^ ((srow & 3) * 8);
    const ushort* bAr = A + (size_t)(bm + srow) * 256 + sgrp;
    const ushort* bA2r = A2 + (size_t)(bm + srow) * 256 + sgrp;
    const ushort* bBr = Bt + (size_t)(bn + srow) * 512 + sgrp;

    const f32x4 z4 = {0.f, 0.f, 0.f, 0.f};
    f32x4 acc[4][4];
    #pragma unroll
    for (int m = 0; m < 4; ++m)
        #pragma unroll
        for (int n = 0; n < 4; ++n) acc[m][n] = z4;

    auto stage = [&](int k0, int b) {           // 4 loads per wave
        char* la = (char*)As[b] + wave * 1024;
        char* lb = (char*)Bs[b] + wave * 1024;
        const ushort* ga = (k0 < 256) ? (bAr + k0) : (bA2r + (k0 - 256));
        gload16(ga, la);
        gload16(ga + 64 * 256, la + 4096);
        gload16(bBr + k0, lb);
        gload16(bBr + k0 + (size_t)64 * 512, lb + 4096);
    };

    stage(0, 0);
    stage(32, 1);
    int cur = 0;
    for (int ti = 0; ti < 16; ++ti) {
        if (ti < 14) {
            stage((ti + 2) * 32, (cur + 2) % 3);
            WAIT_BAR(8);
        } else if (ti == 14) {
            WAIT_BAR(4);
        } else {
            WAIT_BAR(0);
        }
        short8v af[4], bfr[4];
        #pragma unroll
        for (int m = 0; m < 4; ++m) {
            const int r = wr * 64 + m * 16 + lr;
            af[m] = *(const short8v*)&As[cur][r * 32 + (lk ^ ((r & 3) * 8))];
        }
        #pragma unroll
        for (int n = 0; n < 4; ++n) {
            const int r = wc * 64 + n * 16 + lr;
            bfr[n] = *(const short8v*)&Bs[cur][r * 32 + (lk ^ ((r & 3) * 8))];
        }
        #pragma unroll
        for (int m = 0; m < 4; ++m)
            #pragma unroll
            for (int n = 0; n < 4; ++n)
                acc[m][n] = __builtin_amdgcn_mfma_f32_16x16x32_bf16(af[m], bfr[n], acc[m][n], 0, 0, 0);
        END_BAR();
        cur = (cur + 1) % 3;
    }

    const int orow = bm + wr * 64 + (lane >> 4) * 4;
    const int ocol = bn + wc * 64 + lr;
    #pragma unroll
    for (int m = 0; m < 4; ++m)
        #pragma unroll
        for (int n = 0; n < 4; ++n)
            #pragma unroll
            for (int j = 0; j < 4; ++j) {
                const float v = acc[m][n][j];
                O[(size_t)(orow + m * 16 + j) * 512 + ocol + n * 16] = f2b(v > 0.f ? v : 0.f);
            }
}

// ---------------- GEMM + LN + residual (bf16 state), BM=64, BN=256, 3-deep pipeline ----------------
__global__ __launch_bounds__(256) void gemm_ln64(
    const ushort* __restrict__ A, int lda,
    const ushort* __restrict__ Bt,
    const float* __restrict__ g, const float* __restrict__ bb,
    const ushort* __restrict__ resid,        // bf16 pre-layer state
    float* __restrict__ outf,                // fp32 out, last layer only (else null)
    ushort* __restrict__ outb, int K)        // bf16 state out (in-place over resid)
{
    __shared__ __align__(16) ushort As[3][64 * 32];     // 12KB
    __shared__ __align__(16) ushort Bs[3][256 * 32];    // 48KB
    __shared__ float red[2][4][64];
    const int t = threadIdx.x;
    const int wave = t >> 6, lane = t & 63;
    const int bm = blockIdx.x * 64;
    const int lr = lane & 15, kg = lane >> 4, lk = kg * 8;

    const int srow = t >> 2;
    const int sg = ((t & 3) * 8) ^ ((srow & 3) * 8);
    const ushort* aP = A + (size_t)(bm + srow) * lda + sg;
    const ushort* bP = Bt + (size_t)srow * K + sg;
    const size_t b64 = (size_t)64 * K;

    auto stage = [&](int k0, int b) {           // 5 loads per wave
        gload16(aP + k0, (char*)As[b] + wave * 1024);
        char* lb = (char*)Bs[b] + wave * 1024;
        gload16(bP + k0, lb);
        gload16(bP + k0 + b64, lb + 4096);
        gload16(bP + k0 + 2 * b64, lb + 8192);
        gload16(bP + k0 + 3 * b64, lb + 12288);
    };

    const f32x4 z4 = {0.f, 0.f, 0.f, 0.f};
    f32x4 acc[4][4];
    #pragma unroll
    for (int m = 0; m < 4; ++m)
        #pragma unroll
        for (int n = 0; n < 4; ++n) acc[m][n] = z4;

    stage(0, 0);
    stage(32, 1);
    int cur = 0;
    const int NT = K / 32;
    for (int ti = 0; ti < NT; ++ti) {
        if (ti + 2 < NT) {
            stage((ti + 2) * 32, (cur + 2) % 3);
            WAIT_BAR(10);         // 15 outstanding -> oldest 5 (buf[cur]) retired
        } else if (ti + 1 < NT) {
            WAIT_BAR(5);
        } else {
            WAIT_BAR(0);
        }
        short8v af[4], bfr[4];
        #pragma unroll
        for (int m = 0; m < 4; ++m) {
            const int r = m * 16 + lr;
            af[m] = *(const short8v*)&As[cur][r * 32 + (lk ^ ((r & 3) * 8))];
        }
        #pragma unroll
        for (int n = 0; n < 4; ++n) {
            const int r = wave * 64 + n * 16 + lr;
            bfr[n] = *(const short8v*)&Bs[cur][r * 32 + (lk ^ ((r & 3) * 8))];
        }
        #pragma unroll
        for (int m = 0; m < 4; ++m)
            #pragma unroll
            for (int n = 0; n < 4; ++n)
                acc[m][n] = __builtin_amdgcn_mfma_f32_16x16x32_bf16(af[m], bfr[n], acc[m][n], 0, 0, 0);
        END_BAR();
        cur = (cur + 1) % 3;
    }

    #pragma unroll
    for (int m = 0; m < 4; ++m)
        #pragma unroll
        for (int j = 0; j < 4; ++j) {
            float s = 0.f, q = 0.f;
            #pragma unroll
            for (int n = 0; n < 4; ++n) { const float v = acc[m][n][j]; s += v; q += v * v; }
            #pragma unroll
            for (int mk = 1; mk < 16; mk <<= 1) { s += __shfl_xor(s, mk); q += __shfl_xor(q, mk); }
            if (lr == 0) {
                red[0][wave][m * 16 + kg * 4 + j] = s;
                red[1][wave][m * 16 + kg * 4 + j] = q;
            }
        }
    __syncthreads();

    float gv[4], bv[4];
    #pragma unroll
    for (int n = 0; n < 4; ++n) {
        const int col = wave * 64 + n * 16 + lr;
        gv[n] = g[col]; bv[n] = bb[col];
    }
    const ushort* rxb = resid + (size_t)bm * CDIM;

    #pragma unroll
    for (int m = 0; m < 4; ++m)
        #pragma unroll
        for (int j = 0; j < 4; ++j) {
            const int row = m * 16 + kg * 4 + j;
            const float tot = red[0][0][row] + red[0][1][row] + red[0][2][row] + red[0][3][row];
            const float tq  = red[1][0][row] + red[1][1][row] + red[1][2][row] + red[1][3][row];
            const float mu = tot * (1.0f / 256.0f);
            const float var = tq * (1.0f / 256.0f) - mu * mu;
            const float inv = rsqrtf(var + 1e-5f);
            const size_t go = (size_t)(bm + row) * CDIM;
            #pragma unroll
            for (int n = 0; n < 4; ++n) {
                const int col = wave * 64 + n * 16 + lr;
                float val = (acc[m][n][j] - mu) * inv * gv[n] + bv[n];
                val += b2f(rxb[(size_t)row * CDIM + col]);
                if (outf) outf[go + col] = val;
                outb[go + col] = f2b(val);
            }
        }
}

// ---------------- fused attention + Wm GEMM + LN1, BM=64 (R10 structure, unchanged) ----------------
__global__ __launch_bounds__(256) void attn_wm_ln(
    const ushort* __restrict__ Qb, const ushort* __restrict__ KVbT,
    const ushort* __restrict__ Ksb, const ushort* __restrict__ WmT,
    const float* __restrict__ g, const float* __restrict__ bb,
    ushort* __restrict__ mln, int xorv)
{
    __shared__ __align__(16) ushort Ms[64 * 256];     // 32KB
    __shared__ __align__(16) ushort Bs[2][256 * 32];  // 32KB
    __shared__ float red[2][4][64];
    const int t = threadIdx.x, wave = t >> 6, lane = t & 63;
    const int bm = blockIdx.x * 64;
    const int n = bm / SLEN, src = n ^ xorv;
    const int lr = lane & 15, kg = lane >> 4, lk = kg * 8;
    const f32x4 z4 = {0.f, 0.f, 0.f, 0.f};

    const int srow = t >> 2;
    const int sg = ((t & 3) * 8) ^ ((srow & 3) * 8);
    const ushort* bP = WmT + (size_t)srow * 256 + sg;
    auto stageB = [&](int k0, int b) {
        char* lb = (char*)Bs[b] + wave * 1024;
        gload16(bP + k0, lb);
        gload16(bP + k0 + 64 * 256, lb + 4096);
        gload16(bP + k0 + 128 * 256, lb + 8192);
        gload16(bP + k0 + 192 * 256, lb + 12288);
    };
    stageB(0, 0);   // hides under phase-1 MFMAs

    // phase 1: each wave computes 16 rows x all 8 heads into Ms (swizzled)
    {
        const int rw = wave * 16;
        const size_t qrow = ((size_t)bm + rw + lr) * CDIM;
        char* mb = (char*)Ms;
        #pragma unroll
        for (int h = 0; h < NHEAD; ++h) {
            const short8v af = *(const short8v*)&Qb[qrow + h * 32 + kg * 8];
            const ushort* bbp = KVbT + ((size_t)(src * NHEAD + h)) * 1024;
            const short8v b0 = *(const short8v*)&bbp[lr * 32 + kg * 8];
            const short8v b1 = *(const short8v*)&bbp[(16 + lr) * 32 + kg * 8];
            const short8v bz = *(const short8v*)&Ksb[((size_t)(src * NHEAD + h)) * 512 + lr * 32 + kg * 8];
            f32x4 a0 = __builtin_amdgcn_mfma_f32_16x16x32_bf16(af, b0, z4, 0, 0, 0);
            f32x4 a1 = __builtin_amdgcn_mfma_f32_16x16x32_bf16(af, b1, z4, 0, 0, 0);
            f32x4 az = __builtin_amdgcn_mfma_f32_16x16x32_bf16(af, bz, z4, 0, 0, 0);
            #pragma unroll
            for (int j = 0; j < 4; ++j) {
                const float zj = __shfl(az[j], lane & 48);
                const float rz = 1.0f / (zj + 1e-6f);
                const int orow = rw + kg * 4 + j;
                const int swz = (orow & 7) << 4;
                *(ushort*)(mb + ((orow * 512 + (h * 32 + lr) * 2) ^ swz)) = f2b(a0[j] * rz);
                *(ushort*)(mb + ((orow * 512 + (h * 32 + 16 + lr) * 2) ^ swz)) = f2b(a1[j] * rz);
            }
        }
    }
    __syncthreads();

    // phase 2: mln = LN(msg @ Wm), K=256, BM=64, 2-phase staging
    f32x4 acc[4][4];
    #pragma unroll
    for (int m = 0; m < 4; ++m)
        #pragma unroll
        for (int nn = 0; nn < 4; ++nn) acc[m][nn] = z4;

    int cur = 0;
    for (int k0 = 0; k0 < 256; k0 += 32) {
        if (k0 + 32 < 256) stageB(k0 + 32, cur ^ 1);
        short8v af[4], bfr[4];
        #pragma unroll
        for (int m = 0; m < 4; ++m) {
            const int r = m * 16 + lr;
            af[m] = *(const short8v*)((char*)Ms + ((r * 512 + k0 * 2 + kg * 16) ^ ((r & 7) << 4)));
        }
        #pragma unroll
        for (int nn = 0; nn < 4; ++nn) {
            const int r = wave * 64 + nn * 16 + lr;
            bfr[nn] = *(const short8v*)&Bs[cur][r * 32 + (lk ^ ((r & 3) * 8))];
        }
        #pragma unroll
        for (int m = 0; m < 4; ++m)
            #pragma unroll
            for (int nn = 0; nn < 4; ++nn)
                acc[m][nn] = __builtin_amdgcn_mfma_f32_16x16x32_bf16(af[m], bfr[nn], acc[m][nn], 0, 0, 0);
        __syncthreads();
        cur ^= 1;
    }

    #pragma unroll
    for (int m = 0; m < 4; ++m)
        #pragma unroll
        for (int j = 0; j < 4; ++j) {
            float s = 0.f, q = 0.f;
            #pragma unroll
            for (int nn = 0; nn < 4; ++nn) { const float v = acc[m][nn][j]; s += v; q += v * v; }
            #pragma unroll
            for (int mk = 1; mk < 16; mk <<= 1) { s += __shfl_xor(s, mk); q += __shfl_xor(q, mk); }
            if (lr == 0) {
                red[0][wave][m * 16 + kg * 4 + j] = s;
                red[1][wave][m * 16 + kg * 4 + j] = q;
            }
        }
    __syncthreads();

    float gv[4], bv[4];
    #pragma unroll
    for (int nn = 0; nn < 4; ++nn) {
        const int col = wave * 64 + nn * 16 + lr;
        gv[nn] = g[col]; bv[nn] = bb[col];
    }
    #pragma unroll
    for (int m = 0; m < 4; ++m)
        #pragma unroll
        for (int j = 0; j < 4; ++j) {
            const int row = m * 16 + kg * 4 + j;
            const float tot = red[0][0][row] + red[0][1][row] + red[0][2][row] + red[0][3][row];
            const float tq  = red[1][0][row] + red[1][1][row] + red[1][2][row] + red[1][3][row];
            const float mu = tot * (1.0f / 256.0f);
            const float var = tq * (1.0f / 256.0f) - mu * mu;
            const float inv = rsqrtf(var + 1e-5f);
            const size_t go = (size_t)(bm + row) * CDIM;
            #pragma unroll
            for (int nn = 0; nn < 4; ++nn) {
                const int col = wave * 64 + nn * 16 + lr;
                mln[go + col] = f2b((acc[m][nn][j] - mu) * inv * gv[nn] + bv[nn]);
            }
        }
}

// ---------------- weight transpose + bf16: src [L][R][C] -> dst [L(dstride)][C][R] ----------------
__global__ __launch_bounds__(256) void wconv_t(
    const float* __restrict__ src, ushort* __restrict__ dst, int R, int C, size_t dstride)
{
    __shared__ float tile[32][33];
    const int l = blockIdx.z;
    const int r0 = blockIdx.y * 32, c0 = blockIdx.x * 32;
    const int tx = threadIdx.x & 31, ty = threadIdx.x >> 5;
    const float* s = src + (size_t)l * R * C;
    ushort* d = dst + (size_t)l * dstride;
    for (int i = ty; i < 32; i += 8) tile[i][tx] = s[(size_t)(r0 + i) * C + c0 + tx];
    __syncthreads();
    for (int i = ty; i < 32; i += 8) d[(size_t)(c0 + i) * R + r0 + tx] = f2b(tile[tx][i]);
}

// ---------------- KV partial reduction (bf16 in, fp32 partials) ----------------
__global__ __launch_bounds__(256) void kv_part_k(
    const ushort* __restrict__ Kb, const ushort* __restrict__ Vb,
    float* __restrict__ KVp, float* __restrict__ Ksp)
{
    const int blk = blockIdx.x;
    const int seg = blk % SEG;
    const int h = (blk / SEG) % NHEAD;
    const int n = blk / (SEG * NHEAD);
    const int s0 = seg * SCHUNK;
    __shared__ float Ks[16][32];
    __shared__ float Vs[16][32];
    const int t = threadIdx.x;
    const int rr = t >> 4, c2 = (t & 15) * 2;
    const int d = t >> 3, v0 = (t & 7) * 4;
    float a0 = 0, a1 = 0, a2 = 0, a3 = 0, ksum = 0;
    for (int c = 0; c < SCHUNK; c += 16) {
        const size_t off = ((size_t)(n * SLEN + s0 + c + rr)) * CDIM + h * 32 + c2;
        const ushort2 ku = *(const ushort2*)&Kb[off];
        const ushort2 vu = *(const ushort2*)&Vb[off];
        Ks[rr][c2] = b2f(ku.x); Ks[rr][c2 + 1] = b2f(ku.y);
        Vs[rr][c2] = b2f(vu.x); Vs[rr][c2 + 1] = b2f(vu.y);
        __syncthreads();
        #pragma unroll
        for (int q = 0; q < 16; ++q) {
            const float kd = Ks[q][d];
            a0 += kd * Vs[q][v0 + 0];
            a1 += kd * Vs[q][v0 + 1];
            a2 += kd * Vs[q][v0 + 2];
            a3 += kd * Vs[q][v0 + 3];
        }
        if (t < 32) {
            #pragma unroll
            for (int q = 0; q < 16; ++q) ksum += Ks[q][t];
        }
        __syncthreads();
    }
    float* kvp = KVp + ((size_t)((n * NHEAD + h) * SEG + seg)) * 1024;
    kvp[t * 4 + 0] = a0;
    kvp[t * 4 + 1] = a1;
    kvp[t * 4 + 2] = a2;
    kvp[t * 4 + 3] = a3;
    if (t < 32) Ksp[((size_t)((n * NHEAD + h) * SEG + seg)) * 32 + t] = ksum;
}

// ---------------- KV reduce -> bf16 transposed KV + Ksum B-tiles ----------------
__global__ __launch_bounds__(256) void kv_reduce_k(
    const float* __restrict__ KVp, const float* __restrict__ Ksp,
    ushort* __restrict__ KVbT, ushort* __restrict__ Ksb)
{
    const int nh = blockIdx.x;
    const int t = threadIdx.x;
    #pragma unroll
    for (int i = 0; i < 4; ++i) {
        const int idx = t * 4 + i;
        const int v = idx >> 5, d = idx & 31;
        float s = 0;
        for (int seg = 0; seg < SEG; ++seg)
            s += KVp[((size_t)(nh * SEG + seg)) * 1024 + d * 32 + v];
        KVbT[(size_t)nh * 1024 + idx] = f2b(s);
    }
    #pragma unroll
    for (int i = 0; i < 2; ++i) {
        const int idx = t * 2 + i;
        const int c = idx >> 5, d = idx & 31;
        float s = 0;
        if (c == 0)
            for (int seg = 0; seg < SEG; ++seg)
                s += Ksp[((size_t)(nh * SEG + seg)) * 32 + d];
        Ksb[(size_t)nh * 512 + idx] = f2b(s);
    }
}

// ---------------- fp32 -> bf16 convert ----------------
__global__ __launch_bounds__(256) void cvt_in_k(const float* __restrict__ src, ushort* __restrict__ dst) {
    const size_t i = ((size_t)blockIdx.x * 256 + threadIdx.x) * 4;
    const float4 v = *(const float4*)&src[i];
    ushort4 ob = make_ushort4(f2b(v.x), f2b(v.y), f2b(v.z), f2b(v.w));
    *(ushort4*)&dst[i] = ob;
}

// ---------------- host-side orchestration ----------------
struct Ws {
    float *KVp, *Ksp;
    ushort *xb, *Qb, *Kb, *Vb, *h1b, *KVbT, *Ksb;
    ushort *WqkvT, *WmT, *W1T, *W2T;
};

static void layer_pass(float* destf, int xorv,
                       const ushort* WqkvT, const ushort* WmT,
                       const ushort* W1T, const ushort* W2T,
                       const float* g1, const float* b1,
                       const float* g2, const float* b2,
                       const Ws& w, hipStream_t stream)
{
    const dim3 blk(256);
    // 1. Q|K|V = split(xb @ [Wq|Wk|Wv]) over all 38400 rows
    qkv_gemm<<<dim3(6, RALL / 128), blk, 0, stream>>>(w.xb, WqkvT, w.Qb, w.Kb, w.Vb);
    // 2-3. per-batch KV aggregate (pre-layer state both halves -> cross-safe)
    kv_part_k<<<dim3(NB * NHEAD * SEG), blk, 0, stream>>>(w.Kb, w.Vb, w.KVp, w.Ksp);
    kv_reduce_k<<<dim3(NB * NHEAD), blk, 0, stream>>>(w.KVp, w.Ksp, w.KVbT, w.Ksb);
    // 4. mln = LN(attn_msg @ Wm) -> Kb (raw K dead)
    attn_wm_ln<<<dim3(RALL / 64), blk, 0, stream>>>(
        w.Qb, w.KVbT, w.Ksb, WmT, g1, b1, w.Kb, xorv);
    // 5. h1 = relu(concat(xb, mln) @ W1)
    w1_gemm<<<dim3(4, RALL / 128), blk, 0, stream>>>(w.xb, w.Kb, W1T, w.h1b);
    // 6. x' = xb + LN(h1 @ W2) -> xb (bf16, in place); fp32 out only on last layer
    gemm_ln64<<<dim3(RALL / 64), blk, 0, stream>>>(
        w.h1b, 512, W2T, g2, b2, w.xb, destf, w.xb, 512);
}

extern "C" void kernel_launch(void* const* d_in, const int* in_sizes, int n_in,
                              void* d_out, int out_size, void* d_ws, size_t ws_size,
                              hipStream_t stream) {
    (void)in_sizes; (void)n_in; (void)out_size; (void)ws_size;
    const float* f0in = (const float*)d_in[0];
    const float* f1in = (const float*)d_in[1];
    const float* WqA = (const float*)d_in[2];
    const float* WkA = (const float*)d_in[3];
    const float* WvA = (const float*)d_in[4];
    const float* WmA = (const float*)d_in[5];
    const float* W1A = (const float*)d_in[6];
    const float* W2A = (const float*)d_in[7];
    const float* g1A = (const float*)d_in[8];
    const float* b1A = (const float*)d_in[9];
    const float* g2A = (const float*)d_in[10];
    const float* b2A = (const float*)d_in[11];

    float* outf = (float*)d_out;                 // [RALL][256] = out0 | out1
    const size_t RC = (size_t)RTOT * CDIM;
    const size_t RAC = (size_t)RALL * CDIM;

    float* wsf = (float*)d_ws;
    Ws w;
    w.KVp = wsf;                                  // 64*SEG*1024 fp32
    w.Ksp = w.KVp + (size_t)64 * SEG * 1024;      // 64*SEG*32 fp32
    ushort* p = (ushort*)(w.Ksp + 64 * SEG * 32);
    w.xb = p;   p += RAC;
    w.Qb = p;   p += RAC;
    w.Kb = p;   p += RAC;
    w.Vb = p;   p += RAC;
    w.h1b = p;  p += (size_t)RALL * 512;
    w.KVbT = p; p += 64 * 1024;
    w.Ksb = p;  p += 64 * 512;
    w.WqkvT = p; p += (size_t)8 * 768 * 256;
    w.WmT = p;  p += (size_t)8 * 256 * 256;
    w.W1T = p;  p += (size_t)8 * 512 * 512;
    w.W2T = p;  p += (size_t)8 * 512 * 256;

    const dim3 blk(256);
    wconv_t<<<dim3(8, 8, 8), blk, 0, stream>>>(WqA, w.WqkvT,             256, 256, 768 * 256);
    wconv_t<<<dim3(8, 8, 8), blk, 0, stream>>>(WkA, w.WqkvT + 256 * 256, 256, 256, 768 * 256);
    wconv_t<<<dim3(8, 8, 8), blk, 0, stream>>>(WvA, w.WqkvT + 512 * 256, 256, 256, 768 * 256);
    wconv_t<<<dim3(8, 8, 8), blk, 0, stream>>>(WmA, w.WmT, 256, 256, 65536);
    wconv_t<<<dim3(16, 16, 8), blk, 0, stream>>>(W1A, w.W1T, 512, 512, 262144);
    wconv_t<<<dim3(8, 16, 8), blk, 0, stream>>>(W2A, w.W2T, 512, 256, 131072);

    cvt_in_k<<<dim3(RC / 1024), blk, 0, stream>>>(f0in, w.xb);
    cvt_in_k<<<dim3(RC / 1024), blk, 0, stream>>>(f1in, w.xb + RC);

    for (int l = 0; l < 8; ++l) {
        const int xorv = (l & 1) ? 4 : 0;                 // cross layers swap KV source
        float* destf = (l == 7) ? outf : nullptr;
        layer_pass(destf, xorv,
                   w.WqkvT + (size_t)l * 768 * 256,
                   w.WmT + (size_t)l * 65536,
                   w.W1T + (size_t)l * 262144,
                   w.W2T + (size_t)l * 131072,
                   g1A + l * 256, b1A + l * 256, g2A + l * 256, b2A + l * 256,
                   w, stream);
    }
}

// Round 15
// 1388.991 us; speedup vs baseline: 1.0843x; 1.0843x over previous
//
#include <hip/hip_runtime.h>
#include <math.h>

#define RTOT 19200          // rows per feature map (4*4800)
#define RALL 38400          // both feature maps batched
#define CDIM 256
#define SLEN 4800
#define NB 8                // total batches (0-3 = feat0, 4-7 = feat1)
#define NHEAD 8
#define SEG 25
#define SCHUNK 192          // SLEN/SEG

typedef __attribute__((ext_vector_type(8))) short short8v;
typedef __attribute__((ext_vector_type(4))) float f32x4;

__device__ __forceinline__ ushort f2b(float f) {           // fp32 -> bf16 RNE
    unsigned u = __float_as_uint(f);
    unsigned r = (u + 0x7FFFu + ((u >> 16) & 1u)) >> 16;
    return (ushort)r;
}
__device__ __forceinline__ float b2f(ushort u) {
    return __uint_as_float(((unsigned)u) << 16);
}

__device__ __forceinline__ float elu1(float v) { return v > 0.0f ? v + 1.0f : __expf(v); }

__device__ __forceinline__ void gload16(const void* g, void* l) {
    __builtin_amdgcn_global_load_lds((const __attribute__((address_space(1))) void*)g,
                                     (__attribute__((address_space(3))) void*)l, 16, 0, 0);
}

// ---------------- QKV GEMM: split(xb @ [Wq|Wk|Wv]), 2-phase pipelined staging ----------------
__global__ __launch_bounds__(256) void qkv_gemm(
    const ushort* __restrict__ A, const ushort* __restrict__ Bt,
    ushort* __restrict__ Oq, ushort* __restrict__ Ok, ushort* __restrict__ Ov)
{
    __shared__ __align__(16) ushort As[2][128 * 32];
    __shared__ __align__(16) ushort Bs[2][128 * 32];
    const int t = threadIdx.x;
    const int wave = t >> 6, lane = t & 63;
    const int bm = blockIdx.y * 128, bn = blockIdx.x * 128;
    const int wr = wave >> 1, wc = wave & 1;
    const int lr = lane & 15, lk = (lane >> 4) * 8;

    const int srow = t >> 2;
    const int sgrp = ((t & 3) * 8) ^ ((srow & 3) * 8);
    const ushort* bAr = A + (size_t)(bm + srow) * 256 + sgrp;
    const ushort* bBr = Bt + (size_t)(bn + srow) * 256 + sgrp;

    const f32x4 z4 = {0.f, 0.f, 0.f, 0.f};
    f32x4 acc[4][4];
    #pragma unroll
    for (int m = 0; m < 4; ++m)
        #pragma unroll
        for (int n = 0; n < 4; ++n) acc[m][n] = z4;

    auto stage = [&](int k0, int b) {
        char* la = (char*)As[b] + wave * 1024;
        char* lb = (char*)Bs[b] + wave * 1024;
        gload16(bAr + k0, la);
        gload16(bAr + k0 + 64 * 256, la + 4096);
        gload16(bBr + k0, lb);
        gload16(bBr + k0 + 64 * 256, lb + 4096);
    };

    stage(0, 0);
    __syncthreads();
    int cur = 0;
    for (int k0 = 0; k0 < 256; k0 += 32) {
        if (k0 + 32 < 256) stage(k0 + 32, cur ^ 1);
        short8v af[4], bfr[4];
        #pragma unroll
        for (int m = 0; m < 4; ++m) {
            const int r = wr * 64 + m * 16 + lr;
            af[m] = *(const short8v*)&As[cur][r * 32 + (lk ^ ((r & 3) * 8))];
        }
        #pragma unroll
        for (int n = 0; n < 4; ++n) {
            const int r = wc * 64 + n * 16 + lr;
            bfr[n] = *(const short8v*)&Bs[cur][r * 32 + (lk ^ ((r & 3) * 8))];
        }
        #pragma unroll
        for (int m = 0; m < 4; ++m)
            #pragma unroll
            for (int n = 0; n < 4; ++n)
                acc[m][n] = __builtin_amdgcn_mfma_f32_16x16x32_bf16(af[m], bfr[n], acc[m][n], 0, 0, 0);
        __syncthreads();
        cur ^= 1;
    }

    const int orow = bm + wr * 64 + (lane >> 4) * 4;
    const int ocol = bn + wc * 64 + lr;
    #pragma unroll
    for (int m = 0; m < 4; ++m)
        #pragma unroll
        for (int n = 0; n < 4; ++n)
            #pragma unroll
            for (int j = 0; j < 4; ++j) {
                const float v = acc[m][n][j];
                const size_t row = (size_t)(orow + m * 16 + j);
                const int col = ocol + n * 16;
                const int seg = col >> 8, c = col & 255;
                ushort* dst = seg == 0 ? Oq : (seg == 1 ? Ok : Ov);
                dst[row * 256 + c] = f2b(seg < 2 ? elu1(v) : v);
            }
}

// ---------------- W1 GEMM: h1 = relu(concat(xb, mln) @ W1), 128x128 tile, 2-phase staging ----------------
__global__ __launch_bounds__(256) void w1_gemm(
    const ushort* __restrict__ A, const ushort* __restrict__ A2,
    const ushort* __restrict__ Bt, ushort* __restrict__ O)
{
    __shared__ __align__(16) ushort As[2][128 * 32];
    __shared__ __align__(16) ushort Bs[2][128 * 32];
    const int t = threadIdx.x;
    const int wave = t >> 6, lane = t & 63;
    const int bm = blockIdx.y * 128, bn = blockIdx.x * 128;
    const int wr = wave >> 1, wc = wave & 1;
    const int lr = lane & 15, lk = (lane >> 4) * 8;

    const int srow = t >> 2;
    const int sgrp = ((t & 3) * 8) ^ ((srow & 3) * 8);
    const ushort* bAr = A + (size_t)(bm + srow) * 256 + sgrp;
    const ushort* bA2r = A2 + (size_t)(bm + srow) * 256 + sgrp;
    const ushort* bBr = Bt + (size_t)(bn + srow) * 512 + sgrp;

    const f32x4 z4 = {0.f, 0.f, 0.f, 0.f};
    f32x4 acc[4][4];
    #pragma unroll
    for (int m = 0; m < 4; ++m)
        #pragma unroll
        for (int n = 0; n < 4; ++n) acc[m][n] = z4;

    auto stage = [&](int k0, int b) {
        char* la = (char*)As[b] + wave * 1024;
        char* lb = (char*)Bs[b] + wave * 1024;
        const ushort* ga = (k0 < 256) ? (bAr + k0) : (bA2r + (k0 - 256));
        gload16(ga, la);
        gload16(ga + 64 * 256, la + 4096);
        gload16(bBr + k0, lb);
        gload16(bBr + k0 + (size_t)64 * 512, lb + 4096);
    };

    stage(0, 0);
    __syncthreads();
    int cur = 0;
    for (int k0 = 0; k0 < 512; k0 += 32) {
        if (k0 + 32 < 512) stage(k0 + 32, cur ^ 1);
        short8v af[4], bfr[4];
        #pragma unroll
        for (int m = 0; m < 4; ++m) {
            const int r = wr * 64 + m * 16 + lr;
            af[m] = *(const short8v*)&As[cur][r * 32 + (lk ^ ((r & 3) * 8))];
        }
        #pragma unroll
        for (int n = 0; n < 4; ++n) {
            const int r = wc * 64 + n * 16 + lr;
            bfr[n] = *(const short8v*)&Bs[cur][r * 32 + (lk ^ ((r & 3) * 8))];
        }
        #pragma unroll
        for (int m = 0; m < 4; ++m)
            #pragma unroll
            for (int n = 0; n < 4; ++n)
                acc[m][n] = __builtin_amdgcn_mfma_f32_16x16x32_bf16(af[m], bfr[n], acc[m][n], 0, 0, 0);
        __syncthreads();
        cur ^= 1;
    }

    const int orow = bm + wr * 64 + (lane >> 4) * 4;
    const int ocol = bn + wc * 64 + lr;
    #pragma unroll
    for (int m = 0; m < 4; ++m)
        #pragma unroll
        for (int n = 0; n < 4; ++n)
            #pragma unroll
            for (int j = 0; j < 4; ++j) {
                const float v = acc[m][n][j];
                O[(size_t)(orow + m * 16 + j) * 512 + ocol + n * 16] = f2b(v > 0.f ? v : 0.f);
            }
}

// ---------------- GEMM + LN + residual (bf16 state), BM=64, BN=256, 2-phase staging ----------------
__global__ __launch_bounds__(256) void gemm_ln64(
    const ushort* __restrict__ A, int lda,
    const ushort* __restrict__ Bt,
    const float* __restrict__ g, const float* __restrict__ bb,
    const ushort* __restrict__ resid,        // bf16 pre-layer state
    float* __restrict__ outf,                // fp32 out, last layer only (else null)
    ushort* __restrict__ outb, int K)        // bf16 state out (in-place over resid)
{
    __shared__ __align__(16) ushort As[2][64 * 32];
    __shared__ __align__(16) ushort Bs[2][256 * 32];
    __shared__ float red[2][4][64];
    const int t = threadIdx.x;
    const int wave = t >> 6, lane = t & 63;
    const int bm = blockIdx.x * 64;
    const int lr = lane & 15, kg = lane >> 4, lk = kg * 8;

    const int srow = t >> 2;
    const int sg = ((t & 3) * 8) ^ ((srow & 3) * 8);
    const ushort* aP = A + (size_t)(bm + srow) * lda + sg;
    const ushort* bP = Bt + (size_t)srow * K + sg;
    const size_t b64 = (size_t)64 * K;

    auto stage = [&](int k0, int b) {
        gload16(aP + k0, (char*)As[b] + wave * 1024);   // rows 16*wave..16*wave+15
        char* lb = (char*)Bs[b] + wave * 1024;
        gload16(bP + k0, lb);
        gload16(bP + k0 + b64, lb + 4096);
        gload16(bP + k0 + 2 * b64, lb + 8192);
        gload16(bP + k0 + 3 * b64, lb + 12288);
    };

    const f32x4 z4 = {0.f, 0.f, 0.f, 0.f};
    f32x4 acc[4][4];
    #pragma unroll
    for (int m = 0; m < 4; ++m)
        #pragma unroll
        for (int n = 0; n < 4; ++n) acc[m][n] = z4;

    stage(0, 0);
    __syncthreads();
    int cur = 0;
    for (int k0 = 0; k0 < K; k0 += 32) {
        if (k0 + 32 < K) stage(k0 + 32, cur ^ 1);
        short8v af[4], bfr[4];
        #pragma unroll
        for (int m = 0; m < 4; ++m) {
            const int r = m * 16 + lr;
            af[m] = *(const short8v*)&As[cur][r * 32 + (lk ^ ((r & 3) * 8))];
        }
        #pragma unroll
        for (int n = 0; n < 4; ++n) {
            const int r = wave * 64 + n * 16 + lr;
            bfr[n] = *(const short8v*)&Bs[cur][r * 32 + (lk ^ ((r & 3) * 8))];
        }
        #pragma unroll
        for (int m = 0; m < 4; ++m)
            #pragma unroll
            for (int n = 0; n < 4; ++n)
                acc[m][n] = __builtin_amdgcn_mfma_f32_16x16x32_bf16(af[m], bfr[n], acc[m][n], 0, 0, 0);
        __syncthreads();
        cur ^= 1;
    }

    #pragma unroll
    for (int m = 0; m < 4; ++m)
        #pragma unroll
        for (int j = 0; j < 4; ++j) {
            float s = 0.f, q = 0.f;
            #pragma unroll
            for (int n = 0; n < 4; ++n) { const float v = acc[m][n][j]; s += v; q += v * v; }
            #pragma unroll
            for (int mk = 1; mk < 16; mk <<= 1) { s += __shfl_xor(s, mk); q += __shfl_xor(q, mk); }
            if (lr == 0) {
                red[0][wave][m * 16 + kg * 4 + j] = s;
                red[1][wave][m * 16 + kg * 4 + j] = q;
            }
        }
    __syncthreads();

    float gv[4], bv[4];
    #pragma unroll
    for (int n = 0; n < 4; ++n) {
        const int col = wave * 64 + n * 16 + lr;
        gv[n] = g[col]; bv[n] = bb[col];
    }
    const ushort* rxb = resid + (size_t)bm * CDIM;

    #pragma unroll
    for (int m = 0; m < 4; ++m)
        #pragma unroll
        for (int j = 0; j < 4; ++j) {
            const int row = m * 16 + kg * 4 + j;
            const float tot = red[0][0][row] + red[0][1][row] + red[0][2][row] + red[0][3][row];
            const float tq  = red[1][0][row] + red[1][1][row] + red[1][2][row] + red[1][3][row];
            const float mu = tot * (1.0f / 256.0f);
            const float var = tq * (1.0f / 256.0f) - mu * mu;
            const float inv = rsqrtf(var + 1e-5f);
            const size_t go = (size_t)(bm + row) * CDIM;
            #pragma unroll
            for (int n = 0; n < 4; ++n) {
                const int col = wave * 64 + n * 16 + lr;
                float val = (acc[m][n][j] - mu) * inv * gv[n] + bv[n];
                val += b2f(rxb[(size_t)row * CDIM + col]);
                if (outf) outf[go + col] = val;
                outb[go + col] = f2b(val);
            }
        }
}

// ---------------- fused attention + Wm GEMM + LN1, BM=64 ----------------
__global__ __launch_bounds__(256) void attn_wm_ln(
    const ushort* __restrict__ Qb, const ushort* __restrict__ KVbT,
    const ushort* __restrict__ Ksb, const ushort* __restrict__ WmT,
    const float* __restrict__ g, const float* __restrict__ bb,
    ushort* __restrict__ mln, int xorv)
{
    __shared__ __align__(16) ushort Ms[64 * 256];     // 32KB
    __shared__ __align__(16) ushort Bs[2][256 * 32];  // 32KB
    __shared__ float red[2][4][64];
    const int t = threadIdx.x, wave = t >> 6, lane = t & 63;
    const int bm = blockIdx.x * 64;
    const int n = bm / SLEN, src = n ^ xorv;
    const int lr = lane & 15, kg = lane >> 4, lk = kg * 8;
    const f32x4 z4 = {0.f, 0.f, 0.f, 0.f};

    const int srow = t >> 2;
    const int sg = ((t & 3) * 8) ^ ((srow & 3) * 8);
    const ushort* bP = WmT + (size_t)srow * 256 + sg;
    auto stageB = [&](int k0, int b) {
        char* lb = (char*)Bs[b] + wave * 1024;
        gload16(bP + k0, lb);
        gload16(bP + k0 + 64 * 256, lb + 4096);
        gload16(bP + k0 + 128 * 256, lb + 8192);
        gload16(bP + k0 + 192 * 256, lb + 12288);
    };
    stageB(0, 0);   // hides under phase-1 MFMAs

    // phase 1: each wave computes 16 rows x all 8 heads into Ms (swizzled)
    {
        const int rw = wave * 16;
        const size_t qrow = ((size_t)bm + rw + lr) * CDIM;
        char* mb = (char*)Ms;
        #pragma unroll
        for (int h = 0; h < NHEAD; ++h) {
            const short8v af = *(const short8v*)&Qb[qrow + h * 32 + kg * 8];
            const ushort* bbp = KVbT + ((size_t)(src * NHEAD + h)) * 1024;
            const short8v b0 = *(const short8v*)&bbp[lr * 32 + kg * 8];
            const short8v b1 = *(const short8v*)&bbp[(16 + lr) * 32 + kg * 8];
            const short8v bz = *(const short8v*)&Ksb[((size_t)(src * NHEAD + h)) * 512 + lr * 32 + kg * 8];
            f32x4 a0 = __builtin_amdgcn_mfma_f32_16x16x32_bf16(af, b0, z4, 0, 0, 0);
            f32x4 a1 = __builtin_amdgcn_mfma_f32_16x16x32_bf16(af, b1, z4, 0, 0, 0);
            f32x4 az = __builtin_amdgcn_mfma_f32_16x16x32_bf16(af, bz, z4, 0, 0, 0);
            #pragma unroll
            for (int j = 0; j < 4; ++j) {
                const float zj = __shfl(az[j], lane & 48);
                const float rz = 1.0f / (zj + 1e-6f);
                const int orow = rw + kg * 4 + j;
                const int swz = (orow & 7) << 4;
                *(ushort*)(mb + ((orow * 512 + (h * 32 + lr) * 2) ^ swz)) = f2b(a0[j] * rz);
                *(ushort*)(mb + ((orow * 512 + (h * 32 + 16 + lr) * 2) ^ swz)) = f2b(a1[j] * rz);
            }
        }
    }
    __syncthreads();

    // phase 2: mln = LN(msg @ Wm), K=256, BM=64, 2-phase staging
    f32x4 acc[4][4];
    #pragma unroll
    for (int m = 0; m < 4; ++m)
        #pragma unroll
        for (int nn = 0; nn < 4; ++nn) acc[m][nn] = z4;

    int cur = 0;
    for (int k0 = 0; k0 < 256; k0 += 32) {
        if (k0 + 32 < 256) stageB(k0 + 32, cur ^ 1);
        short8v af[4], bfr[4];
        #pragma unroll
        for (int m = 0; m < 4; ++m) {
            const int r = m * 16 + lr;
            af[m] = *(const short8v*)((char*)Ms + ((r * 512 + k0 * 2 + kg * 16) ^ ((r & 7) << 4)));
        }
        #pragma unroll
        for (int nn = 0; nn < 4; ++nn) {
            const int r = wave * 64 + nn * 16 + lr;
            bfr[nn] = *(const short8v*)&Bs[cur][r * 32 + (lk ^ ((r & 3) * 8))];
        }
        #pragma unroll
        for (int m = 0; m < 4; ++m)
            #pragma unroll
            for (int nn = 0; nn < 4; ++nn)
                acc[m][nn] = __builtin_amdgcn_mfma_f32_16x16x32_bf16(af[m], bfr[nn], acc[m][nn], 0, 0, 0);
        __syncthreads();
        cur ^= 1;
    }

    #pragma unroll
    for (int m = 0; m < 4; ++m)
        #pragma unroll
        for (int j = 0; j < 4; ++j) {
            float s = 0.f, q = 0.f;
            #pragma unroll
            for (int nn = 0; nn < 4; ++nn) { const float v = acc[m][nn][j]; s += v; q += v * v; }
            #pragma unroll
            for (int mk = 1; mk < 16; mk <<= 1) { s += __shfl_xor(s, mk); q += __shfl_xor(q, mk); }
            if (lr == 0) {
                red[0][wave][m * 16 + kg * 4 + j] = s;
                red[1][wave][m * 16 + kg * 4 + j] = q;
            }
        }
    __syncthreads();

    float gv[4], bv[4];
    #pragma unroll
    for (int nn = 0; nn < 4; ++nn) {
        const int col = wave * 64 + nn * 16 + lr;
        gv[nn] = g[col]; bv[nn] = bb[col];
    }
    #pragma unroll
    for (int m = 0; m < 4; ++m)
        #pragma unroll
        for (int j = 0; j < 4; ++j) {
            const int row = m * 16 + kg * 4 + j;
            const float tot = red[0][0][row] + red[0][1][row] + red[0][2][row] + red[0][3][row];
            const float tq  = red[1][0][row] + red[1][1][row] + red[1][2][row] + red[1][3][row];
            const float mu = tot * (1.0f / 256.0f);
            const float var = tq * (1.0f / 256.0f) - mu * mu;
            const float inv = rsqrtf(var + 1e-5f);
            const size_t go = (size_t)(bm + row) * CDIM;
            #pragma unroll
            for (int nn = 0; nn < 4; ++nn) {
                const int col = wave * 64 + nn * 16 + lr;
                mln[go + col] = f2b((acc[m][nn][j] - mu) * inv * gv[nn] + bv[nn]);
            }
        }
}

// ---------------- weight transpose + bf16: src [L][R][C] -> dst [L(dstride)][C][R] ----------------
__global__ __launch_bounds__(256) void wconv_t(
    const float* __restrict__ src, ushort* __restrict__ dst, int R, int C, size_t dstride)
{
    __shared__ float tile[32][33];
    const int l = blockIdx.z;
    const int r0 = blockIdx.y * 32, c0 = blockIdx.x * 32;
    const int tx = threadIdx.x & 31, ty = threadIdx.x >> 5;
    const float* s = src + (size_t)l * R * C;
    ushort* d = dst + (size_t)l * dstride;
    for (int i = ty; i < 32; i += 8) tile[i][tx] = s[(size_t)(r0 + i) * C + c0 + tx];
    __syncthreads();
    for (int i = ty; i < 32; i += 8) d[(size_t)(c0 + i) * R + r0 + tx] = f2b(tile[tx][i]);
}

// ---------------- KV partial reduction (bf16 in, fp32 partials) ----------------
__global__ __launch_bounds__(256) void kv_part_k(
    const ushort* __restrict__ Kb, const ushort* __restrict__ Vb,
    float* __restrict__ KVp, float* __restrict__ Ksp)
{
    const int blk = blockIdx.x;
    const int seg = blk % SEG;
    const int h = (blk / SEG) % NHEAD;
    const int n = blk / (SEG * NHEAD);
    const int s0 = seg * SCHUNK;
    __shared__ float Ks[16][32];
    __shared__ float Vs[16][32];
    const int t = threadIdx.x;
    const int rr = t >> 4, c2 = (t & 15) * 2;
    const int d = t >> 3, v0 = (t & 7) * 4;
    float a0 = 0, a1 = 0, a2 = 0, a3 = 0, ksum = 0;
    for (int c = 0; c < SCHUNK; c += 16) {
        const size_t off = ((size_t)(n * SLEN + s0 + c + rr)) * CDIM + h * 32 + c2;
        const ushort2 ku = *(const ushort2*)&Kb[off];
        const ushort2 vu = *(const ushort2*)&Vb[off];
        Ks[rr][c2] = b2f(ku.x); Ks[rr][c2 + 1] = b2f(ku.y);
        Vs[rr][c2] = b2f(vu.x); Vs[rr][c2 + 1] = b2f(vu.y);
        __syncthreads();
        #pragma unroll
        for (int q = 0; q < 16; ++q) {
            const float kd = Ks[q][d];
            a0 += kd * Vs[q][v0 + 0];
            a1 += kd * Vs[q][v0 + 1];
            a2 += kd * Vs[q][v0 + 2];
            a3 += kd * Vs[q][v0 + 3];
        }
        if (t < 32) {
            #pragma unroll
            for (int q = 0; q < 16; ++q) ksum += Ks[q][t];
        }
        __syncthreads();
    }
    float* kvp = KVp + ((size_t)((n * NHEAD + h) * SEG + seg)) * 1024;
    kvp[t * 4 + 0] = a0;
    kvp[t * 4 + 1] = a1;
    kvp[t * 4 + 2] = a2;
    kvp[t * 4 + 3] = a3;
    if (t < 32) Ksp[((size_t)((n * NHEAD + h) * SEG + seg)) * 32 + t] = ksum;
}

// ---------------- KV reduce -> bf16 transposed KV + Ksum B-tiles ----------------
__global__ __launch_bounds__(256) void kv_reduce_k(
    const float* __restrict__ KVp, const float* __restrict__ Ksp,
    ushort* __restrict__ KVbT, ushort* __restrict__ Ksb)
{
    const int nh = blockIdx.x;
    const int t = threadIdx.x;
    #pragma unroll
    for (int i = 0; i < 4; ++i) {
        const int idx = t * 4 + i;
        const int v = idx >> 5, d = idx & 31;
        float s = 0;
        for (int seg = 0; seg < SEG; ++seg)
            s += KVp[((size_t)(nh * SEG + seg)) * 1024 + d * 32 + v];
        KVbT[(size_t)nh * 1024 + idx] = f2b(s);
    }
    #pragma unroll
    for (int i = 0; i < 2; ++i) {
        const int idx = t * 2 + i;
        const int c = idx >> 5, d = idx & 31;
        float s = 0;
        if (c == 0)
            for (int seg = 0; seg < SEG; ++seg)
                s += Ksp[((size_t)(nh * SEG + seg)) * 32 + d];
        Ksb[(size_t)nh * 512 + idx] = f2b(s);
    }
}

// ---------------- fp32 -> bf16 convert ----------------
__global__ __launch_bounds__(256) void cvt_in_k(const float* __restrict__ src, ushort* __restrict__ dst) {
    const size_t i = ((size_t)blockIdx.x * 256 + threadIdx.x) * 4;
    const float4 v = *(const float4*)&src[i];
    ushort4 ob = make_ushort4(f2b(v.x), f2b(v.y), f2b(v.z), f2b(v.w));
    *(ushort4*)&dst[i] = ob;
}

// ---------------- host-side orchestration ----------------
struct Ws {
    float *KVp, *Ksp;
    ushort *xb, *Qb, *Kb, *Vb, *h1b, *KVbT, *Ksb;
    ushort *WqkvT, *WmT, *W1T, *W2T;
};

static void layer_pass(float* destf, int xorv,
                       const ushort* WqkvT, const ushort* WmT,
                       const ushort* W1T, const ushort* W2T,
                       const float* g1, const float* b1,
                       const float* g2, const float* b2,
                       const Ws& w, hipStream_t stream)
{
    const dim3 blk(256);
    // 1. Q|K|V = split(xb @ [Wq|Wk|Wv]) over all 38400 rows
    qkv_gemm<<<dim3(6, RALL / 128), blk, 0, stream>>>(w.xb, WqkvT, w.Qb, w.Kb, w.Vb);
    // 2-3. per-batch KV aggregate (pre-layer state both halves -> cross-safe)
    kv_part_k<<<dim3(NB * NHEAD * SEG), blk, 0, stream>>>(w.Kb, w.Vb, w.KVp, w.Ksp);
    kv_reduce_k<<<dim3(NB * NHEAD), blk, 0, stream>>>(w.KVp, w.Ksp, w.KVbT, w.Ksb);
    // 4. mln = LN(attn_msg @ Wm) -> Kb (raw K dead)
    attn_wm_ln<<<dim3(RALL / 64), blk, 0, stream>>>(
        w.Qb, w.KVbT, w.Ksb, WmT, g1, b1, w.Kb, xorv);
    // 5. h1 = relu(concat(xb, mln) @ W1)
    w1_gemm<<<dim3(4, RALL / 128), blk, 0, stream>>>(w.xb, w.Kb, W1T, w.h1b);
    // 6. x' = xb + LN(h1 @ W2) -> xb (bf16, in place); fp32 out only on last layer
    gemm_ln64<<<dim3(RALL / 64), blk, 0, stream>>>(
        w.h1b, 512, W2T, g2, b2, w.xb, destf, w.xb, 512);
}

extern "C" void kernel_launch(void* const* d_in, const int* in_sizes, int n_in,
                              void* d_out, int out_size, void* d_ws, size_t ws_size,
                              hipStream_t stream) {
    (void)in_sizes; (void)n_in; (void)out_size; (void)ws_size;
    const float* f0in = (const float*)d_in[0];
    const float* f1in = (const float*)d_in[1];
    const float* WqA = (const float*)d_in[2];
    const float* WkA = (const float*)d_in[3];
    const float* WvA = (const float*)d_in[4];
    const float* WmA = (const float*)d_in[5];
    const float* W1A = (const float*)d_in[6];
    const float* W2A = (const float*)d_in[7];
    const float* g1A = (const float*)d_in[8];
    const float* b1A = (const float*)d_in[9];
    const float* g2A = (const float*)d_in[10];
    const float* b2A = (const float*)d_in[11];

    float* outf = (float*)d_out;                 // [RALL][256] = out0 | out1
    const size_t RC = (size_t)RTOT * CDIM;
    const size_t RAC = (size_t)RALL * CDIM;

    float* wsf = (float*)d_ws;
    Ws w;
    w.KVp = wsf;                                  // 64*SEG*1024 fp32
    w.Ksp = w.KVp + (size_t)64 * SEG * 1024;      // 64*SEG*32 fp32
    ushort* p = (ushort*)(w.Ksp + 64 * SEG * 32);
    w.xb = p;   p += RAC;
    w.Qb = p;   p += RAC;
    w.Kb = p;   p += RAC;
    w.Vb = p;   p += RAC;
    w.h1b = p;  p += (size_t)RALL * 512;
    w.KVbT = p; p += 64 * 1024;
    w.Ksb = p;  p += 64 * 512;
    w.WqkvT = p; p += (size_t)8 * 768 * 256;
    w.WmT = p;  p += (size_t)8 * 256 * 256;
    w.W1T = p;  p += (size_t)8 * 512 * 512;
    w.W2T = p;  p += (size_t)8 * 512 * 256;

    const dim3 blk(256);
    wconv_t<<<dim3(8, 8, 8), blk, 0, stream>>>(WqA, w.WqkvT,             256, 256, 768 * 256);
    wconv_t<<<dim3(8, 8, 8), blk, 0, stream>>>(WkA, w.WqkvT + 256 * 256, 256, 256, 768 * 256);
    wconv_t<<<dim3(8, 8, 8), blk, 0, stream>>>(WvA, w.WqkvT + 512 * 256, 256, 256, 768 * 256);
    wconv_t<<<dim3(8, 8, 8), blk, 0, stream>>>(WmA, w.WmT, 256, 256, 65536);
    wconv_t<<<dim3(16, 16, 8), blk, 0, stream>>>(W1A, w.W1T, 512, 512, 262144);
    wconv_t<<<dim3(8, 16, 8), blk, 0, stream>>>(W2A, w.W2T, 512, 256, 131072);

    cvt_in_k<<<dim3(RC / 1024), blk, 0, stream>>>(f0in, w.xb);
    cvt_in_k<<<dim3(RC / 1024), blk, 0, stream>>>(f1in, w.xb + RC);

    for (int l = 0; l < 8; ++l) {
        const int xorv = (l & 1) ? 4 : 0;                 // cross layers swap KV source
        float* destf = (l == 7) ? outf : nullptr;
        layer_pass(destf, xorv,
                   w.WqkvT + (size_t)l * 768 * 256,
                   w.WmT + (size_t)l * 65536,
                   w.W1T + (size_t)l * 262144,
                   w.W2T + (size_t)l * 131072,
                   g1A + l * 256, b1A + l * 256, g2A + l * 256, b2A + l * 256,
                   w, stream);
    }
}